// Round 1
// baseline (9164.537 us; speedup 1.0000x reference)
//
#include <hip/hip_runtime.h>
#include <hip/hip_bf16.h>
#include <cstddef>

#define B_ 128
#define T_ 512
#define I_ 64
#define H_ 512

typedef __attribute__((ext_vector_type(8))) short short8v;
typedef __attribute__((ext_vector_type(4))) float f32x4;

__device__ __forceinline__ unsigned short f2bf(float f) {
  union { float f; unsigned u; } v; v.f = f;
  unsigned r = (v.u + 0x7FFFu + ((v.u >> 16) & 1u)) >> 16;
  return (unsigned short)r;
}
__device__ __forceinline__ float sigm(float x) { return 1.0f / (1.0f + __expf(-x)); }
__device__ __forceinline__ float tanh_(float x) {
  float t = __expf(2.0f * x);
  return 1.0f - 2.0f / (t + 1.0f);
}

// One LSTM layer, persistent grouped kernel.
// Grid: 256 WGs x 256 threads (cooperative). Group g = blockIdx>>5 owns batch
// rows [16g,16g+16); CU c = blockIdx&31 owns h-cols [16c,16c+16) (=64 gate rows).
// Weights [W_ih|W_hh] for owned rows live in LDS (bf16, XOR-swizzled).
// h ping-pong through agent-scope (LLC-coherent) buffer; split-counter group barrier.
template<int PASS>
__global__ __launch_bounds__(256, 1)
void lstm_pass(const float* __restrict__ Wih, const float* __restrict__ Whh,
               const float* __restrict__ bih, const float* __restrict__ bhh,
               const float* __restrict__ xf32,          // PASS 0: x [B][T][64] fp32
               const unsigned short* __restrict__ xbf,  // PASS 1: h1 [T][B][512] bf16
               unsigned int* __restrict__ hhist,        // PASS 0 out: h1 [T][B][H/2] u32(bf16x2)
               float* __restrict__ h2last,              // PASS 1 out: [B][H] fp32
               unsigned int* __restrict__ hcomm,        // [2][B][H/2] u32(bf16x2)
               unsigned int* __restrict__ cnts)         // group g: cnts[g*64 + q*16], q=0..3
{
  constexpr int KIN = (PASS == 0) ? I_ : H_;
  constexpr int KW  = KIN + H_;                  // 576 / 1024
  constexpr int KWS = (PASS == 0) ? 640 : 1024;  // row padded to 64-elem multiple (128B) for bijective swizzle
  constexpr int NKI = KIN / 32;                  // 2 / 16
  constexpr int NK  = KW / 32;                   // 18 / 32

  __shared__ unsigned short Wl[4 * 16 * KWS];    // [type][hcol][k], swizzled
  __shared__ unsigned short Ah[16 * H_];         // h_prev [batch][k], swizzled
  __shared__ float accS[4][16][16];              // [type][batch][hcol]

  const int tid  = threadIdx.x;
  const int wave = tid >> 6;
  const int lane = tid & 63;
  const int lrow = lane & 15;
  const int kgrp = lane >> 4;
  const int g    = blockIdx.x >> 5;
  const int c    = blockIdx.x & 31;
  const int BG0  = g * 16;
  const int HC0  = c * 16;

  // ---- stage weights (once) ----
  for (int idx = tid; idx < 4 * 16 * KW; idx += 256) {
    int k  = idx % KW;
    int rj = idx / KW;
    int jj = rj & 15;
    int w  = rj >> 4;
    int grow = w * H_ + HC0 + jj;                // global gate row (i,f,g,o blocks)
    float wv = (k < KIN) ? Wih[(size_t)grow * KIN + k]
                         : Whh[(size_t)grow * H_ + (k - KIN)];
    int byteoff = ((w * 16 + jj) * KWS + k) * 2;
    byteoff ^= ((jj & 7) << 4);
    *(unsigned short*)((char*)Wl + byteoff) = f2bf(wv);
  }

  const int growB = wave * H_ + HC0 + lrow;
  const float bias = bih[growB] + bhh[growB];

  const int m = tid >> 4;   // batch-in-group for cell update
  const int j = tid & 15;   // hcol-in-CU for cell update
  float cst = 0.0f;         // persistent fp32 cell state

  unsigned int* cg = cnts + g * 64;

  __syncthreads();          // Wl ready

  for (int t = 0; t < T_; ++t) {
    // ---- stage h_prev (coherent loads from ping-pong buffer) into swizzled LDS ----
    {
      const unsigned long long* src =
          (const unsigned long long*)(hcomm + ((t + 1) & 1) * (B_ * H_ / 2));
      #pragma unroll
      for (int q = 0; q < 8; ++q) {
        unsigned long long v = __hip_atomic_load(
            src + (size_t)(BG0 + m) * (H_ / 4) + j * 8 + q,
            __ATOMIC_RELAXED, __HIP_MEMORY_SCOPE_AGENT);
        int byteoff = (m * H_ + j * 32 + q * 4) * 2;
        byteoff ^= ((m & 7) << 4);
        *(unsigned long long*)((char*)Ah + byteoff) = v;
      }
    }
    __syncthreads();

    // ---- gates = [x_t | h_prev] @ W_slice^T  (wave w computes gate-type w) ----
    f32x4 acc = {0.f, 0.f, 0.f, 0.f};
    #pragma unroll
    for (int kk = 0; kk < NK; ++kk) {
      short8v a, b;
      if (kk < NKI) {
        if (PASS == 0) {
          const float* xp = xf32 + ((size_t)(BG0 + lrow) * T_ + t) * I_ + kk * 32 + kgrp * 8;
          #pragma unroll
          for (int e = 0; e < 8; ++e) a[e] = (short)f2bf(xp[e]);
        } else {
          a = *(const short8v*)(xbf + ((size_t)t * B_ + BG0 + lrow) * H_ + kk * 32 + kgrp * 8);
        }
      } else {
        int byteoff = (lrow * H_ + (kk - NKI) * 32 + kgrp * 8) * 2;
        byteoff ^= ((lrow & 7) << 4);
        a = *(const short8v*)((const char*)Ah + byteoff);
      }
      {
        int byteoff = ((wave * 16 + lrow) * KWS + kk * 32 + kgrp * 8) * 2;
        byteoff ^= ((lrow & 7) << 4);
        b = *(const short8v*)((const char*)Wl + byteoff);
      }
      acc = __builtin_amdgcn_mfma_f32_16x16x32_bf16(a, b, acc, 0, 0, 0);
    }
    // D layout: col = lane&15 (gate col), row = (lane>>4)*4 + r (batch)
    #pragma unroll
    for (int r = 0; r < 4; ++r) accS[wave][kgrp * 4 + r][lrow] = acc[r] + bias;
    __syncthreads();

    // ---- cell update: thread owns (batch m, hcol j) ----
    float xi = accS[0][m][j], xfv = accS[1][m][j], xg = accS[2][m][j], xo = accS[3][m][j];
    float iv = sigm(xi), fv = sigm(xfv), gv = tanh_(xg), ov = sigm(xo);
    cst = fv * cst + iv * gv;
    float hv = ov * tanh_(cst);

    unsigned int hb = f2bf(hv);
    unsigned int ob = ((unsigned int)__shfl_xor((int)hb, 1, 64)) & 0xFFFFu;
    if (!(j & 1)) {
      unsigned int u = (ob << 16) | hb;        // little-endian: cols {j, j+1}
      int uidx = ((BG0 + m) * H_ + HC0 + j) >> 1;
      __hip_atomic_store(hcomm + (t & 1) * (B_ * H_ / 2) + uidx, u,
                         __ATOMIC_RELAXED, __HIP_MEMORY_SCOPE_AGENT);
      if (PASS == 0)
        hhist[((size_t)t * B_ + BG0 + m) * (H_ / 2) + ((HC0 + j) >> 1)] = u;
    }
    if (PASS == 1 && t == T_ - 1)
      h2last[(BG0 + m) * H_ + HC0 + j] = hv;

    // ---- group barrier (release arrive / acquire leave) ----
    if (t < T_ - 1) {
      __syncthreads();   // drains all threads' vmem (incl. agent stores) per-wave
      if (tid == 0) {
        __hip_atomic_fetch_add(cg + (c & 3) * 16, 1u,
                               __ATOMIC_RELEASE, __HIP_MEMORY_SCOPE_AGENT);
        const unsigned int target = 32u * (unsigned)(t + 1);
        for (;;) {
          unsigned int s = 0;
          #pragma unroll
          for (int qq = 0; qq < 4; ++qq)
            s += __hip_atomic_load(cg + qq * 16, __ATOMIC_RELAXED, __HIP_MEMORY_SCOPE_AGENT);
          if (s >= target) break;
        }
        __builtin_amdgcn_fence(__ATOMIC_ACQUIRE, "agent");
      }
      __syncthreads();
    }
  }
}

__global__ void out_proj(const float* __restrict__ h2last,
                         const float* __restrict__ Wout,
                         const float* __restrict__ bout,
                         float* __restrict__ out) {
  int o = blockIdx.x;            // 0..383 = b*3+cc
  int b = o / 3, cc = o - b * 3;
  int ln = threadIdx.x;          // 64
  float s = 0.f;
  #pragma unroll
  for (int k = ln; k < H_; k += 64) s += h2last[b * H_ + k] * Wout[cc * H_ + k];
  #pragma unroll
  for (int off = 32; off; off >>= 1) s += __shfl_down(s, off, 64);
  if (ln == 0) out[o] = s + bout[cc];
}

extern "C" void kernel_launch(void* const* d_in, const int* in_sizes, int n_in,
                              void* d_out, int out_size, void* d_ws, size_t ws_size,
                              hipStream_t stream) {
  (void)in_sizes; (void)n_in; (void)out_size; (void)ws_size;
  const float* x    = (const float*)d_in[0];
  const float* Wih0 = (const float*)d_in[1];
  const float* Whh0 = (const float*)d_in[2];
  const float* bih0 = (const float*)d_in[3];
  const float* bhh0 = (const float*)d_in[4];
  const float* Wih1 = (const float*)d_in[5];
  const float* Whh1 = (const float*)d_in[6];
  const float* bih1 = (const float*)d_in[7];
  const float* bhh1 = (const float*)d_in[8];
  const float* Wout = (const float*)d_in[9];
  const float* bout = (const float*)d_in[10];

  char* ws = (char*)d_ws;
  unsigned int* h1ws   = (unsigned int*)(ws);             // 67,108,864 B: h1 [T][B][H] bf16
  float*        h2last = (float*)(ws + 67108864);         // 262,144 B
  unsigned int* hcommA = (unsigned int*)(ws + 67371008);  // 262,144 B
  unsigned int* hcommB = (unsigned int*)(ws + 67633152);  // 262,144 B
  unsigned int* cnts   = (unsigned int*)(ws + 67895296);  // 4,096 B

  // zero comm buffers + counters every launch (h_init=0, deterministic replays)
  hipMemsetAsync(ws + 67371008, 0, 262144 * 2 + 4096, stream);

  {
    const unsigned short* xbf_null = nullptr;
    float* h2_null = nullptr;
    unsigned int* cA = cnts;
    void* args[10] = {
      (void*)&Wih0, (void*)&Whh0, (void*)&bih0, (void*)&bhh0,
      (void*)&x, (void*)&xbf_null, (void*)&h1ws, (void*)&h2_null,
      (void*)&hcommA, (void*)&cA
    };
    hipLaunchCooperativeKernel(reinterpret_cast<const void*>(&lstm_pass<0>),
                               dim3(256), dim3(256), args, 0, stream);
  }
  {
    const float* xf_null = nullptr;
    const unsigned short* h1bf = (const unsigned short*)h1ws;
    unsigned int* hh_null = nullptr;
    unsigned int* cB = cnts + 512;
    void* args[10] = {
      (void*)&Wih1, (void*)&Whh1, (void*)&bih1, (void*)&bhh1,
      (void*)&xf_null, (void*)&h1bf, (void*)&hh_null, (void*)&h2last,
      (void*)&hcommB, (void*)&cB
    };
    hipLaunchCooperativeKernel(reinterpret_cast<const void*>(&lstm_pass<1>),
                               dim3(256), dim3(256), args, 0, stream);
  }
  out_proj<<<dim3(384), dim3(64), 0, stream>>>(h2last, Wout, bout, (float*)d_out);
}